// Round 5
// baseline (132.835 us; speedup 1.0000x reference)
//
#include <hip/hip_runtime.h>
#include <hip/hip_bf16.h>

// Problem constants (fixed by setup_inputs)
#define NSAMP 16384   // N
#define BB    4       // batch
#define C2D   128
#define C3D   128
#define HH    96
#define WW    160
#define COUT  128
#define KK    256
#define TN    64      // samples per fuse block
#define HW    (HH*WW) // 15360

typedef __attribute__((ext_vector_type(8))) short bf16x8;  // MFMA A/B frag
typedef __attribute__((ext_vector_type(4))) float f32x4;   // MFMA C/D frag

__device__ __forceinline__ float bf16lo(unsigned int u) { return __uint_as_float(u << 16); }
__device__ __forceinline__ float bf16hi(unsigned int u) { return __uint_as_float(u & 0xffff0000u); }
__device__ __forceinline__ unsigned int pack2(float a, float b) {
    union { __hip_bfloat162 h; unsigned int u; } c;
    c.h = __float22bfloat162_rn(make_float2(a, b));   // RNE, a in low 16
    return c.u;
}
// Convert 8 consecutive fp32 (two float4) -> bf16x8 A-fragment.
__device__ __forceinline__ bf16x8 cvt8(const float4 x, const float4 y) {
    union { uint4 u; bf16x8 v; } c;
    c.u.x = pack2(x.x, x.y);
    c.u.y = pack2(x.z, x.w);
    c.u.z = pack2(y.x, y.y);
    c.u.w = pack2(y.z, y.w);
    return c.v;
}
// 16B-group XOR swizzle for 64-word LDS rows: conflict-free b128 frags.
#define SWZ(n, g) ((g) ^ ((n) & 7))

// ---------------------------------------------------------------------------
// Kernel 1: G = bf16(W[:, :128] @ f2d) per batch, channel-last [B,HW,COUT].
// Bilinear sampling is linear per channel: W2d @ bilerp(f2d) == bilerp(G).
// Block = 64 hw. 256 thr = 4 waves; wave wv -> co [32wv,32wv+32).
// A-fragments: Wm fp32 loaded directly (L2-hot), converted in registers.
// Epilogue: direct uint2 stores (L2 merges into full lines) — no LDS pass.
// ---------------------------------------------------------------------------
__global__ __launch_bounds__(256, 4) void gemm1_kernel(
    const float* __restrict__ f2d,   // [B,C2D,H,W]
    const float* __restrict__ Wm,    // [COUT,KK] fp32
    unsigned short* __restrict__ G)  // [B,HW,COUT] bf16
{
    __shared__ unsigned short sB[64 * 128];   // [hw][ch] bf16, XOR-swizzled

    const int tid  = threadIdx.x;
    const int lane = tid & 63;
    const int wv   = tid >> 6;
    const int blk  = blockIdx.x;
    const int b    = blk / (HW / 64);
    const int hw0  = (blk % (HW / 64)) * 64;

    // ---- stage f2d tile: wave wv covers 32 channels, lane = hw ----
    {
        const float* src = f2d + (size_t)(b * C2D + wv * 32) * HW + hw0 + lane;
        unsigned int* sBw = (unsigned int*)sB;    // row = 64 uints
        #pragma unroll
        for (int i = 0; i < 4; ++i) {
            float v[8];
            #pragma unroll
            for (int j = 0; j < 8; ++j) v[j] = src[(size_t)(i * 8 + j) * HW];
            uint4 pk;
            pk.x = pack2(v[0], v[1]);
            pk.y = pack2(v[2], v[3]);
            pk.z = pack2(v[4], v[5]);
            pk.w = pack2(v[6], v[7]);
            const int g = wv * 4 + i;             // 16B group (8 channels)
            *(uint4*)&sBw[lane * 64 + SWZ(lane, g) * 4] = pk;
        }
    }
    __syncthreads();

    // ---- MFMA: D[128co x 64hw] = W2d @ tile ----
    const int quad = lane >> 4;
    const int nloc = lane & 15;
    f32x4 acc[2][4];
    #pragma unroll
    for (int mt = 0; mt < 2; ++mt)
        #pragma unroll
        for (int nt = 0; nt < 4; ++nt)
            acc[mt][nt] = (f32x4){0.f, 0.f, 0.f, 0.f};

    const float* w0 = Wm + (size_t)(wv * 32 + nloc) * KK + quad * 8;  // 2D cols 0..127
    #pragma unroll
    for (int ks = 0; ks < 4; ++ks) {
        const bf16x8 a0 = cvt8(*(const float4*)(w0 + ks * 32),
                               *(const float4*)(w0 + ks * 32 + 4));
        const bf16x8 a1 = cvt8(*(const float4*)(w0 + 16 * KK + ks * 32),
                               *(const float4*)(w0 + 16 * KK + ks * 32 + 4));
        #pragma unroll
        for (int nt = 0; nt < 4; ++nt) {
            const int n = nt * 16 + nloc;
            const bf16x8 bf = *(const bf16x8*)
                &sB[n * 128 + SWZ(n, ks * 4 + quad) * 8];
            acc[0][nt] = __builtin_amdgcn_mfma_f32_16x16x32_bf16(a0, bf, acc[0][nt], 0, 0, 0);
            acc[1][nt] = __builtin_amdgcn_mfma_f32_16x16x32_bf16(a1, bf, acc[1][nt], 0, 0, 0);
        }
    }

    // ---- direct bf16 store (C/D: col=hw=nloc, row=co=quad*4+r) ----
    {
        unsigned int* Gw = (unsigned int*)(G + ((size_t)b * HW + hw0) * COUT);
        #pragma unroll
        for (int mt = 0; mt < 2; ++mt) {
            const int cidx = wv * 16 + mt * 8 + quad * 2;   // cobase/2 in uints
            #pragma unroll
            for (int nt = 0; nt < 4; ++nt) {
                const int n = nt * 16 + nloc;
                uint2 pk;
                pk.x = pack2(acc[mt][nt][0], acc[mt][nt][1]);
                pk.y = pack2(acc[mt][nt][2], acc[mt][nt][3]);
                *(uint2*)&Gw[n * 64 + cidx] = pk;
            }
        }
    }
}

// ---------------------------------------------------------------------------
// Kernel 2: out = leaky(bilerp(G) + W[:,128:] @ f3d + b).
// Block = (batch, 64 samples). Gather-blend of G is independent of the f3d
// staging + MFMA stream -> interleaves into load-latency gaps.
// ---------------------------------------------------------------------------
__global__ __launch_bounds__(256, 4) void fuse2_kernel(
    const float*          __restrict__ xy,    // [B,2,N]
    const unsigned short* __restrict__ G,     // [B,HW,COUT] bf16
    const float*          __restrict__ f3d,   // [B,C3D,N]
    const float*          __restrict__ Wm,    // [COUT,KK] fp32
    const float*          __restrict__ bias,  // [COUT]
    float* __restrict__ out)                  // [B,COUT,N]
{
    __shared__ unsigned short sB[64 * 128];   // f3d tile [n][ch], swizzled
    __shared__ unsigned short g2[64 * 136];   // blended 2D contrib [n][co]
    __shared__ float4 sw4[TN];
    __shared__ int4   soff4[TN];

    const int tid  = threadIdx.x;
    const int lane = tid & 63;
    const int wv   = tid >> 6;
    const int blk  = blockIdx.x;
    const int b    = blk >> 8;
    const int n0   = (blk & 255) * TN;

    // ---- Phase 0: bilinear params ----
    if (tid < TN) {
        const int n = n0 + tid;
        float x = xy[((size_t)b * 2 + 0) * NSAMP + n];
        float y = xy[((size_t)b * 2 + 1) * NSAMP + n];
        float xf = floorf(x), yf = floorf(y);
        float wx1 = x - xf, wy1 = y - yf;
        float wx0 = 1.0f - wx1, wy0 = 1.0f - wy1;
        int x0 = (int)xf, y0 = (int)yf;
        int x1 = x0 + 1, y1 = y0 + 1;
        if (x0 < 0 || x0 > WW - 1) wx0 = 0.0f;
        if (x1 < 0 || x1 > WW - 1) wx1 = 0.0f;
        if (y0 < 0 || y0 > HH - 1) wy0 = 0.0f;
        if (y1 < 0 || y1 > HH - 1) wy1 = 0.0f;
        x0 = min(max(x0, 0), WW - 1);
        x1 = min(max(x1, 0), WW - 1);
        y0 = min(max(y0, 0), HH - 1);
        y1 = min(max(y1, 0), HH - 1);
        sw4[tid]   = make_float4(wx0 * wy0, wx1 * wy0, wx0 * wy1, wx1 * wy1);
        soff4[tid] = make_int4(y0 * WW + x0, y0 * WW + x1,
                               y1 * WW + x0, y1 * WW + x1);
    }
    __syncthreads();

    // ---- Phase 1a: stage f3d -> sB [n][ch] bf16 (lane = sample) ----
    {
        const float* p3 = f3d + (size_t)(b * C3D) * NSAMP + n0 + lane;
        unsigned int* sBw = (unsigned int*)sB;
        #pragma unroll
        for (int i = 0; i < 4; ++i) {
            const int cbase = wv * 32 + i * 8;
            float v[8];
            #pragma unroll
            for (int j = 0; j < 8; ++j) v[j] = p3[(size_t)(cbase + j) * NSAMP];
            uint4 pk;
            pk.x = pack2(v[0], v[1]);
            pk.y = pack2(v[2], v[3]);
            pk.z = pack2(v[4], v[5]);
            pk.w = pack2(v[6], v[7]);
            const int g = wv * 4 + i;
            *(uint4*)&sBw[lane * 64 + SWZ(lane, g) * 4] = pk;
        }
    }

    // ---- Phase 1b: gather-blend G corners -> g2[n][co] bf16.
    // Half-wave per sample: lane -> (sample bit s, 4 channels). ----
    {
        const int s   = lane >> 5;
        const int ch4 = (lane & 31) * 4;
        const unsigned short* fb = G + (size_t)b * HW * COUT + ch4;
        #pragma unroll 4
        for (int i = 0; i < 8; ++i) {
            const int j = wv * 16 + i * 2 + s;
            const float4 w = sw4[j];
            const int4   o = soff4[j];
            const uint2 c0v = *(const uint2*)(fb + (size_t)o.x * COUT);
            const uint2 c1v = *(const uint2*)(fb + (size_t)o.y * COUT);
            const uint2 c2v = *(const uint2*)(fb + (size_t)o.z * COUT);
            const uint2 c3v = *(const uint2*)(fb + (size_t)o.w * COUT);
            float r0 = w.x * bf16lo(c0v.x) + w.y * bf16lo(c1v.x)
                     + w.z * bf16lo(c2v.x) + w.w * bf16lo(c3v.x);
            float r1 = w.x * bf16hi(c0v.x) + w.y * bf16hi(c1v.x)
                     + w.z * bf16hi(c2v.x) + w.w * bf16hi(c3v.x);
            float r2 = w.x * bf16lo(c0v.y) + w.y * bf16lo(c1v.y)
                     + w.z * bf16lo(c2v.y) + w.w * bf16lo(c3v.y);
            float r3 = w.x * bf16hi(c0v.y) + w.y * bf16hi(c1v.y)
                     + w.z * bf16hi(c2v.y) + w.w * bf16hi(c3v.y);
            uint2 pk;
            pk.x = pack2(r0, r1);
            pk.y = pack2(r2, r3);
            *(uint2*)&g2[j * 136 + ch4] = pk;
        }
    }
    __syncthreads();

    // ---- Phase 2: MFMA K=128 (3D half) + blended 2D + bias + leaky ----
    {
        const int quad = lane >> 4;
        const int nloc = lane & 15;

        f32x4 acc[2][4];
        #pragma unroll
        for (int mt = 0; mt < 2; ++mt)
            #pragma unroll
            for (int nt = 0; nt < 4; ++nt)
                acc[mt][nt] = (f32x4){0.f, 0.f, 0.f, 0.f};

        // 3D half = Wm cols 128..255, fp32 -> bf16 in registers
        const float* w0 = Wm + (size_t)(wv * 32 + nloc) * KK + C2D + quad * 8;
        #pragma unroll
        for (int ks = 0; ks < 4; ++ks) {
            const bf16x8 a0 = cvt8(*(const float4*)(w0 + ks * 32),
                                   *(const float4*)(w0 + ks * 32 + 4));
            const bf16x8 a1 = cvt8(*(const float4*)(w0 + 16 * KK + ks * 32),
                                   *(const float4*)(w0 + 16 * KK + ks * 32 + 4));
            #pragma unroll
            for (int nt = 0; nt < 4; ++nt) {
                const int n = nt * 16 + nloc;
                const bf16x8 bf = *(const bf16x8*)
                    &sB[n * 128 + SWZ(n, ks * 4 + quad) * 8];
                acc[0][nt] = __builtin_amdgcn_mfma_f32_16x16x32_bf16(a0, bf, acc[0][nt], 0, 0, 0);
                acc[1][nt] = __builtin_amdgcn_mfma_f32_16x16x32_bf16(a1, bf, acc[1][nt], 0, 0, 0);
            }
        }

        // Epilogue (C/D: col=n=nloc, row=co=quad*4+r)
        #pragma unroll
        for (int mt = 0; mt < 2; ++mt) {
            const int cobase = wv * 32 + mt * 16 + quad * 4;
            const float4 bv = *(const float4*)&bias[cobase];
            #pragma unroll
            for (int nt = 0; nt < 4; ++nt) {
                const int n = nt * 16 + nloc;
                const uint2 gq = *(const uint2*)&g2[n * 136 + cobase];
                float add[4] = { bf16lo(gq.x), bf16hi(gq.x),
                                 bf16lo(gq.y), bf16hi(gq.y) };
                float* po = out + (size_t)(b * COUT + cobase) * NSAMP + n0 + n;
                #pragma unroll
                for (int r = 0; r < 4; ++r) {
                    float yv = acc[mt][nt][r] + add[r] + ((const float*)&bv)[r];
                    yv = (yv >= 0.0f) ? yv : 0.1f * yv;
                    po[(size_t)r * NSAMP] = yv;
                }
            }
        }
    }
}

extern "C" void kernel_launch(void* const* d_in, const int* in_sizes, int n_in,
                              void* d_out, int out_size, void* d_ws, size_t ws_size,
                              hipStream_t stream) {
    const float* xy   = (const float*)d_in[0];
    const float* f2d  = (const float*)d_in[1];
    const float* f3d  = (const float*)d_in[2];
    const float* Wm   = (const float*)d_in[3];
    const float* bias = (const float*)d_in[4];
    float* out = (float*)d_out;

    // ws: G bf16 [B*HW*COUT] (15.7 MB)
    unsigned short* G = (unsigned short*)d_ws;

    gemm1_kernel<<<dim3(BB * (HW / 64)), 256, 0, stream>>>(f2d, Wm, G);
    fuse2_kernel<<<dim3(BB * (NSAMP / TN)), 256, 0, stream>>>(
        xy, G, f3d, Wm, bias, out);
}

// Round 6
// 128.015 us; speedup vs baseline: 1.0376x; 1.0376x over previous
//
#include <hip/hip_runtime.h>
#include <hip/hip_bf16.h>

// Problem constants (fixed by setup_inputs)
#define NSAMP 16384   // N
#define BB    4       // batch
#define C2D   128
#define C3D   128
#define HH    96
#define WW    160
#define COUT  128
#define KK    256
#define TN    64      // samples per fuse block
#define HW    (HH*WW) // 15360

typedef __attribute__((ext_vector_type(8))) short bf16x8;  // MFMA A/B frag
typedef __attribute__((ext_vector_type(4))) float f32x4;   // MFMA C/D frag

__device__ __forceinline__ float bf16lo(unsigned int u) { return __uint_as_float(u << 16); }
__device__ __forceinline__ float bf16hi(unsigned int u) { return __uint_as_float(u & 0xffff0000u); }
__device__ __forceinline__ unsigned int pack2(float a, float b) {
    union { __hip_bfloat162 h; unsigned int u; } c;
    c.h = __float22bfloat162_rn(make_float2(a, b));   // RNE, a in low 16
    return c.u;
}
// 16B-group XOR swizzle for 64-word LDS rows: conflict-free b128 frags.
#define SWZ(n, g) ((g) ^ ((n) & 7))

// ---------------------------------------------------------------------------
// Kernel 1: split W fp32 [COUT,KK] into Wb2 = W[:, :128] and Wb3 = W[:,128:],
// both bf16 row-major [128][128].  (Precomputed bf16 fragments beat inline
// fp32 cvt in the K-loops — R5 regression evidence.)
// ---------------------------------------------------------------------------
__global__ __launch_bounds__(256) void wsplit_kernel(
    const float* __restrict__ Wm,
    unsigned short* __restrict__ Wb2, unsigned short* __restrict__ Wb3)
{
    const int idx = blockIdx.x * 256 + threadIdx.x;   // 8192 float4s
    const float4 v = ((const float4*)Wm)[idx];
    uint2 o;
    o.x = pack2(v.x, v.y);
    o.y = pack2(v.z, v.w);
    const int row = idx >> 6;       // KK/4 = 64 float4 per row
    const int c4  = idx & 63;
    if (c4 < 32) ((uint2*)Wb2)[row * 32 + c4]        = o;
    else         ((uint2*)Wb3)[row * 32 + (c4 - 32)] = o;
}

// ---------------------------------------------------------------------------
// Kernel 2: G = bf16(W2d @ f2d) per batch, channel-last [B,HW,COUT].
// Sampling is linear per channel: W2d @ bilerp(f2d) == bilerp(G).
// Block = 64 hw. 256 thr = 4 waves; wave wv -> co [32wv,32wv+32).
// Write-out staged through sO so global stores are 256B-contiguous rows.
// ---------------------------------------------------------------------------
__global__ __launch_bounds__(256, 4) void gemm1_kernel(
    const float*          __restrict__ f2d,   // [B,C2D,H,W]
    const unsigned short* __restrict__ Wb2,   // [COUT,C2D] bf16
    unsigned short*       __restrict__ G)     // [B,HW,COUT] bf16
{
    __shared__ unsigned short sB[64 * 128];   // [hw][ch] bf16, XOR-swizzled
    __shared__ unsigned short sO[64 * 136];   // G tile [hw][co]

    const int tid  = threadIdx.x;
    const int lane = tid & 63;
    const int wv   = tid >> 6;
    const int blk  = blockIdx.x;
    const int b    = blk / (HW / 64);
    const int hw0  = (blk % (HW / 64)) * 64;

    // ---- stage f2d tile: wave wv covers 32 channels, lane = hw ----
    {
        const float* src = f2d + (size_t)(b * C2D + wv * 32) * HW + hw0 + lane;
        unsigned int* sBw = (unsigned int*)sB;    // row = 64 uints
        #pragma unroll
        for (int i = 0; i < 4; ++i) {
            float v[8];
            #pragma unroll
            for (int j = 0; j < 8; ++j) v[j] = src[(size_t)(i * 8 + j) * HW];
            uint4 pk;
            pk.x = pack2(v[0], v[1]);
            pk.y = pack2(v[2], v[3]);
            pk.z = pack2(v[4], v[5]);
            pk.w = pack2(v[6], v[7]);
            const int g = wv * 4 + i;             // 16B group (8 channels)
            *(uint4*)&sBw[lane * 64 + SWZ(lane, g) * 4] = pk;
        }
    }
    __syncthreads();

    // ---- MFMA: D[128co x 64hw] = Wb2 @ tile ----
    const int quad = lane >> 4;
    const int nloc = lane & 15;
    f32x4 acc[2][4];
    #pragma unroll
    for (int mt = 0; mt < 2; ++mt)
        #pragma unroll
        for (int nt = 0; nt < 4; ++nt)
            acc[mt][nt] = (f32x4){0.f, 0.f, 0.f, 0.f};

    const unsigned short* wb0 = Wb2 + (size_t)(wv * 32 + nloc) * C2D + quad * 8;
    #pragma unroll
    for (int ks = 0; ks < 4; ++ks) {
        const bf16x8 a0 = *(const bf16x8*)(wb0 + ks * 32);
        const bf16x8 a1 = *(const bf16x8*)(wb0 + 16 * C2D + ks * 32);
        #pragma unroll
        for (int nt = 0; nt < 4; ++nt) {
            const int n = nt * 16 + nloc;
            const bf16x8 bf = *(const bf16x8*)
                &sB[n * 128 + SWZ(n, ks * 4 + quad) * 8];
            acc[0][nt] = __builtin_amdgcn_mfma_f32_16x16x32_bf16(a0, bf, acc[0][nt], 0, 0, 0);
            acc[1][nt] = __builtin_amdgcn_mfma_f32_16x16x32_bf16(a1, bf, acc[1][nt], 0, 0, 0);
        }
    }

    // ---- pack to bf16 into sO [hw][co] (C/D: col=hw=nloc, row=co=quad*4+r) ----
    #pragma unroll
    for (int mt = 0; mt < 2; ++mt) {
        const int cobase = wv * 32 + mt * 16 + quad * 4;
        #pragma unroll
        for (int nt = 0; nt < 4; ++nt) {
            const int n = nt * 16 + nloc;
            uint2 pk;
            pk.x = pack2(acc[mt][nt][0], acc[mt][nt][1]);
            pk.y = pack2(acc[mt][nt][2], acc[mt][nt][3]);
            *(uint2*)&sO[n * 136 + cobase] = pk;
        }
    }
    __syncthreads();

    // ---- coalesced write-out: row = 256B, 16 lanes x 16B per row ----
    {
        unsigned int* Gw = (unsigned int*)(G + ((size_t)b * HW + hw0) * COUT);
        const int q = tid & 15, r0 = tid >> 4;
        #pragma unroll
        for (int it = 0; it < 4; ++it) {
            const int n = r0 + it * 16;
            const uint4 v = *(const uint4*)&sO[n * 136 + q * 8];
            *(uint4*)&Gw[n * 64 + q * 4] = v;
        }
    }
}

// ---------------------------------------------------------------------------
// Kernel 3: out = leaky(bilerp(G) + W3d @ f3d + b).
// Block = (batch, 64 samples). Single barrier: bilinear params computed
// inline per-lane (half-wave-uniform; xy loads broadcast) — no Phase-0 LDS
// pass, waves issue VMEM immediately at entry.
// ---------------------------------------------------------------------------
__global__ __launch_bounds__(256, 4) void fuse2_kernel(
    const float*          __restrict__ xy,    // [B,2,N]
    const unsigned short* __restrict__ G,     // [B,HW,COUT] bf16
    const float*          __restrict__ f3d,   // [B,C3D,N]
    const unsigned short* __restrict__ Wb3,   // [COUT,C3D] bf16
    const float*          __restrict__ bias,  // [COUT]
    float* __restrict__ out)                  // [B,COUT,N]
{
    __shared__ unsigned short sB[64 * 128];   // f3d tile [n][ch], swizzled
    __shared__ unsigned short g2[64 * 136];   // blended 2D contrib [n][co]

    const int tid  = threadIdx.x;
    const int lane = tid & 63;
    const int wv   = tid >> 6;
    const int blk  = blockIdx.x;
    const int b    = blk >> 8;
    const int n0   = (blk & 255) * TN;

    // ---- Phase 1a: stage f3d -> sB [n][ch] bf16 (lane = sample) ----
    {
        const float* p3 = f3d + (size_t)(b * C3D) * NSAMP + n0 + lane;
        unsigned int* sBw = (unsigned int*)sB;
        #pragma unroll
        for (int i = 0; i < 4; ++i) {
            const int cbase = wv * 32 + i * 8;
            float v[8];
            #pragma unroll
            for (int j = 0; j < 8; ++j) v[j] = p3[(size_t)(cbase + j) * NSAMP];
            uint4 pk;
            pk.x = pack2(v[0], v[1]);
            pk.y = pack2(v[2], v[3]);
            pk.z = pack2(v[4], v[5]);
            pk.w = pack2(v[6], v[7]);
            const int g = wv * 4 + i;
            *(uint4*)&sBw[lane * 64 + SWZ(lane, g) * 4] = pk;
        }
    }

    // ---- Phase 1b: gather-blend G corners -> g2[n][co] bf16.
    // Half-wave per sample: lane -> (sample bit s, 4 channels).
    // Bilinear params computed inline (uniform across the 32-lane half-wave).
    {
        const int s   = lane >> 5;
        const int ch4 = (lane & 31) * 4;
        const unsigned short* fb = G + (size_t)b * HW * COUT + ch4;
        const float* px = xy + (size_t)(b * 2 + 0) * NSAMP + n0;
        const float* py = xy + (size_t)(b * 2 + 1) * NSAMP + n0;
        #pragma unroll 4
        for (int i = 0; i < 8; ++i) {
            const int j = wv * 16 + i * 2 + s;
            // inline bilinear params for sample j
            float x = px[j], y = py[j];
            float xf = floorf(x), yf = floorf(y);
            float wx1 = x - xf, wy1 = y - yf;
            float wx0 = 1.0f - wx1, wy0 = 1.0f - wy1;
            int x0 = (int)xf, y0 = (int)yf;
            int x1 = x0 + 1, y1 = y0 + 1;
            if (x0 < 0 || x0 > WW - 1) wx0 = 0.0f;
            if (x1 < 0 || x1 > WW - 1) wx1 = 0.0f;
            if (y0 < 0 || y0 > HH - 1) wy0 = 0.0f;
            if (y1 < 0 || y1 > HH - 1) wy1 = 0.0f;
            x0 = min(max(x0, 0), WW - 1);
            x1 = min(max(x1, 0), WW - 1);
            y0 = min(max(y0, 0), HH - 1);
            y1 = min(max(y1, 0), HH - 1);
            const float4 w = make_float4(wx0 * wy0, wx1 * wy0, wx0 * wy1, wx1 * wy1);
            const int4   o = make_int4(y0 * WW + x0, y0 * WW + x1,
                                       y1 * WW + x0, y1 * WW + x1);
            const uint2 c0v = *(const uint2*)(fb + (size_t)o.x * COUT);
            const uint2 c1v = *(const uint2*)(fb + (size_t)o.y * COUT);
            const uint2 c2v = *(const uint2*)(fb + (size_t)o.z * COUT);
            const uint2 c3v = *(const uint2*)(fb + (size_t)o.w * COUT);
            float r0 = w.x * bf16lo(c0v.x) + w.y * bf16lo(c1v.x)
                     + w.z * bf16lo(c2v.x) + w.w * bf16lo(c3v.x);
            float r1 = w.x * bf16hi(c0v.x) + w.y * bf16hi(c1v.x)
                     + w.z * bf16hi(c2v.x) + w.w * bf16hi(c3v.x);
            float r2 = w.x * bf16lo(c0v.y) + w.y * bf16lo(c1v.y)
                     + w.z * bf16lo(c2v.y) + w.w * bf16lo(c3v.y);
            float r3 = w.x * bf16hi(c0v.y) + w.y * bf16hi(c1v.y)
                     + w.z * bf16hi(c2v.y) + w.w * bf16hi(c3v.y);
            uint2 pk;
            pk.x = pack2(r0, r1);
            pk.y = pack2(r2, r3);
            *(uint2*)&g2[j * 136 + ch4] = pk;
        }
    }
    __syncthreads();

    // ---- Phase 2: MFMA K=128 (3D half) + blended 2D + bias + leaky ----
    {
        const int quad = lane >> 4;
        const int nloc = lane & 15;

        f32x4 acc[2][4];
        #pragma unroll
        for (int mt = 0; mt < 2; ++mt)
            #pragma unroll
            for (int nt = 0; nt < 4; ++nt)
                acc[mt][nt] = (f32x4){0.f, 0.f, 0.f, 0.f};

        const unsigned short* wb0 = Wb3 + (size_t)(wv * 32 + nloc) * C3D + quad * 8;
        #pragma unroll
        for (int ks = 0; ks < 4; ++ks) {
            const bf16x8 a0 = *(const bf16x8*)(wb0 + ks * 32);
            const bf16x8 a1 = *(const bf16x8*)(wb0 + 16 * C3D + ks * 32);
            #pragma unroll
            for (int nt = 0; nt < 4; ++nt) {
                const int n = nt * 16 + nloc;
                const bf16x8 bf = *(const bf16x8*)
                    &sB[n * 128 + SWZ(n, ks * 4 + quad) * 8];
                acc[0][nt] = __builtin_amdgcn_mfma_f32_16x16x32_bf16(a0, bf, acc[0][nt], 0, 0, 0);
                acc[1][nt] = __builtin_amdgcn_mfma_f32_16x16x32_bf16(a1, bf, acc[1][nt], 0, 0, 0);
            }
        }

        // Epilogue (C/D: col=n=nloc, row=co=quad*4+r)
        #pragma unroll
        for (int mt = 0; mt < 2; ++mt) {
            const int cobase = wv * 32 + mt * 16 + quad * 4;
            const float4 bv = *(const float4*)&bias[cobase];
            #pragma unroll
            for (int nt = 0; nt < 4; ++nt) {
                const int n = nt * 16 + nloc;
                const uint2 gq = *(const uint2*)&g2[n * 136 + cobase];
                float add[4] = { bf16lo(gq.x), bf16hi(gq.x),
                                 bf16lo(gq.y), bf16hi(gq.y) };
                float* po = out + (size_t)(b * COUT + cobase) * NSAMP + n0 + n;
                #pragma unroll
                for (int r = 0; r < 4; ++r) {
                    float yv = acc[mt][nt][r] + add[r] + ((const float*)&bv)[r];
                    yv = (yv >= 0.0f) ? yv : 0.1f * yv;
                    po[(size_t)r * NSAMP] = yv;
                }
            }
        }
    }
}

extern "C" void kernel_launch(void* const* d_in, const int* in_sizes, int n_in,
                              void* d_out, int out_size, void* d_ws, size_t ws_size,
                              hipStream_t stream) {
    const float* xy   = (const float*)d_in[0];
    const float* f2d  = (const float*)d_in[1];
    const float* f3d  = (const float*)d_in[2];
    const float* Wm   = (const float*)d_in[3];
    const float* bias = (const float*)d_in[4];
    float* out = (float*)d_out;

    // ws layout: G bf16 [B*HW*COUT] (15.7 MB), then Wb2, Wb3 (32 KB each).
    unsigned short* G   = (unsigned short*)d_ws;
    unsigned short* Wb2 = G + (size_t)BB * HW * COUT;
    unsigned short* Wb3 = Wb2 + (size_t)COUT * C2D;

    wsplit_kernel<<<dim3(32), 256, 0, stream>>>(Wm, Wb2, Wb3);
    gemm1_kernel<<<dim3(BB * (HW / 64)), 256, 0, stream>>>(f2d, Wb2, G);
    fuse2_kernel<<<dim3(BB * (NSAMP / TN)), 256, 0, stream>>>(
        xy, G, f3d, Wb3, bias, out);
}